// Round 5
// baseline (417.766 us; speedup 1.0000x reference)
//
#include <hip/hip_runtime.h>

// SKANLinear: y[b,o] = sum_{i=0}^{IN} weight[o,i] * sin(w[o,i] * x_ext[b,i])
// x_ext[b,IN] = 1.0. B=2048, IN=256, OUT=256. f32.
//
// R9: occupancy experiment — 8 waves/SIMD (vs R4's 4) to test cross-wave
// trans||VALU pipe overlap. Evidence: R6->R7 delta gives v_sin ~6.5
// cyc/wave64 and a SUM-of-issue model that retrofits R4 at ~10.3us kernel
// (= its floor under that model). If the trans pipe co-issues with the
// main VALU across waves (cf. MFMA||VALU, m114), doubling resident waves
// turns sum (24.5k cyc/SIMD) into max(trans 13.4k, valu ~11k) ~ 6us.
// Changes vs R4: wave = 64 b x 1 o (halves per-wave regs), CHUNK=32
// (xs[32]), VGPR<=64 via __launch_bounds__(256,8), LDS 16.9KB/block x 8
// blocks = 135KB/CU, grid 2048 = exactly 8 blocks/CU (no tail).
// Kept from R4 (proven best): SMEM/SGPR coefficient folding (zero
// coefficient VALU instrs), x pre-scaled by 1/2pi staged through LDS
// (stride-33: 2-way = free), per-lane full (b,o) sums (no reduction),
// single barrier per chunk, depth-1 global prefetch issued pre-barrier.

#define IN_DIM 256
#define OUT_DIM 256
#define LDW 257
#define CHUNK 32
#define NCH 8               // 256 / 32
#define LXS 33              // x-tile row stride (odd -> 2-way bank alias = free)
#define INV_2PI 0.15915494309189535f

__global__ __launch_bounds__(256, 8)
void skan_kernel(const float* __restrict__ x,      // [2048][256]
                 const float* __restrict__ weight, // [256][257]
                 const float* __restrict__ wfreq,  // [256][257]
                 float* __restrict__ y)            // [2048][256]
{
    __shared__ float lx[2][64 * LXS];   // 2 x 8448 B = 16.9 KB

    const int t  = threadIdx.x;
    const int l  = t & 63;                                   // lane = local b
    const int wv = __builtin_amdgcn_readfirstlane(t >> 6);   // wave id, uniform

    const int obase = (blockIdx.x & 63) * 4;    // 64 o-tiles of 4
    const int b0    = (blockIdx.x >> 6) * 64;   // 32 b-tiles of 64
    const int o     = obase + wv;               // ONE o per wave

    const float* __restrict__ wr = wfreq  + o * LDW;  // uniform -> s_load
    const float* __restrict__ gr = weight + o * LDW;

    // bias column (i=256, x_ext=1): every lane owns a full (b,o) sum -> init.
    float acc = gr[IN_DIM] * __builtin_amdgcn_sinf(wr[IN_DIM] * INV_2PI);

    // staging map: thread t -> row t>>2 (64 rows), cols (t&3)*8 .. +7
    // (4 threads cover one 32-float row chunk; global reads fully coalesced)
    const int srow = t >> 2;
    const int scol = (t & 3) * 8;
    const float* xsrc = x + (b0 + srow) * IN_DIM + scol;

    // ---- prologue: stage chunk 0 into buffer 0 ----
    {
        const float4 a = *(const float4*)(xsrc + 0);
        const float4 b = *(const float4*)(xsrc + 4);
        float* d = &lx[0][srow * LXS + scol];
        d[0] = a.x * INV_2PI; d[1] = a.y * INV_2PI;
        d[2] = a.z * INV_2PI; d[3] = a.w * INV_2PI;
        d[4] = b.x * INV_2PI; d[5] = b.y * INV_2PI;
        d[6] = b.z * INV_2PI; d[7] = b.w * INV_2PI;
    }

#pragma unroll
    for (int c = 0; c < NCH; ++c) {
        // issue next chunk's global loads BEFORE the barrier: latency
        // overlaps the barrier wait + this chunk's compute.
        float4 a, b;
        if (c + 1 < NCH) {
            a = *(const float4*)(xsrc + (c + 1) * CHUNK + 0);
            b = *(const float4*)(xsrc + (c + 1) * CHUNK + 4);
        }

        __syncthreads();     // stage(c) visible; all waves done reading buf c^1
        const int cur = c & 1;

        // my b-row's 32 x-values -> regs (ds_read2_b32 pairs, stride-33 free)
        float xs[CHUNK];
#pragma unroll
        for (int j = 0; j < CHUNK; ++j) xs[j] = lx[cur][l * LXS + j];

        // write next chunk into the other buffer (readers retired pre-barrier)
        if (c + 1 < NCH) {
            float* d = &lx[cur ^ 1][srow * LXS + scol];
            d[0] = a.x * INV_2PI; d[1] = a.y * INV_2PI;
            d[2] = a.z * INV_2PI; d[3] = a.w * INV_2PI;
            d[4] = b.x * INV_2PI; d[5] = b.y * INV_2PI;
            d[6] = b.z * INV_2PI; d[7] = b.w * INV_2PI;
        }

        // core: v_mul(s,v) + v_sin + v_fmac(s,v) per element; coefficients
        // fold into VALU operands via the scalar pipe (no coeff VALU instrs).
        const int ib = c * CHUNK;
#pragma unroll
        for (int j = 0; j < CHUNK; ++j)
            acc = fmaf(gr[ib + j], __builtin_amdgcn_sinf(wr[ib + j] * xs[j]), acc);
    }

    // store: one scatter store per wave (64 rows x 1 col)
    y[(b0 + l) * OUT_DIM + o] = acc;
}

extern "C" void kernel_launch(void* const* d_in, const int* in_sizes, int n_in,
                              void* d_out, int out_size, void* d_ws, size_t ws_size,
                              hipStream_t stream) {
    const float* x      = (const float*)d_in[0];
    const float* weight = (const float*)d_in[1];
    const float* wfreq  = (const float*)d_in[2];
    float* y            = (float*)d_out;

    const int B = in_sizes[0] / IN_DIM;                 // 2048
    const int grid = (B / 64) * (OUT_DIM / 4);          // 32 * 64 = 2048

    skan_kernel<<<grid, 256, 0, stream>>>(x, weight, wfreq, y);
}

// Round 6
// 376.215 us; speedup vs baseline: 1.1104x; 1.1104x over previous
//
#include <hip/hip_runtime.h>

// SKANLinear: y[b,o] = sum_{i=0}^{IN} weight[o,i] * sin(w[o,i] * x_ext[b,i])
// x_ext[b,IN] = 1.0. B=2048, IN=256, OUT=256. f32.
//
// R10: R9's 8-waves/SIMD occupancy experiment, de-spilled.
// Evidence: R9's scratch blowup gave the calibration dur = kernel + 40.3
// (fill) + 11.5 (fixed) => R4/R6 kernels are ~25us vs a ~11us issue-sum
// floor (v_sin ~6.5 issue-cyc from the R6->R7 delta). 45% issue efficiency
// at 4 waves/SIMD = stall-bound => occupancy is the right lever; R9 failed
// only because xs[32] spilled under the 64-VGPR cap.
// Fix: NO per-lane x array. Compute reads x directly from LDS (ds_read2,
// lane-stride 33 -> 2-way alias = free). Per-thread regs: acc + 2 float4
// staging temps + addresses ~= 45 < 64 -> real 8 waves/SIMD.
//  - wave = 1 o x 64 b; coefficients via SMEM/SGPR folding (R4-proven)
//  - x pre-scaled by 1/2pi at staging (v_sin takes revolutions)
//  - double-buffered chunks of 32 i, ONE barrier per chunk; global
//    prefetch issued pre-barrier so vmcnt latency hides under compute
//  - LDS 16.9KB x 8 blocks = 135KB/CU; grid 2048 = exactly 8 blocks/CU
// Issue budget/SIMD: sin 13.3k + mul/fma 8.2k + ds ~3k + staging ~2k
// ~= 27k cyc ~= 11us; predict 12-15us kernel at 8-wave latency hiding.

#define IN_DIM 256
#define OUT_DIM 256
#define LDW 257
#define CHUNK 32
#define NCH 8               // 256 / 32
#define LXS 33              // x-tile row stride (odd -> 2-way bank alias = free)
#define INV_2PI 0.15915494309189535f

__global__ __launch_bounds__(256, 8)
void skan_kernel(const float* __restrict__ x,      // [2048][256]
                 const float* __restrict__ weight, // [256][257]
                 const float* __restrict__ wfreq,  // [256][257]
                 float* __restrict__ y)            // [2048][256]
{
    __shared__ float lx[2][64 * LXS];   // 2 x 8448 B = 16.9 KB

    const int t  = threadIdx.x;
    const int l  = t & 63;                                   // lane = local b
    const int wv = __builtin_amdgcn_readfirstlane(t >> 6);   // wave id, uniform

    const int obase = (blockIdx.x & 63) * 4;    // 64 o-tiles of 4
    const int b0    = (blockIdx.x >> 6) * 64;   // 32 b-tiles of 64
    const int o     = obase + wv;               // ONE o per wave

    const float* __restrict__ wr = wfreq  + o * LDW;  // uniform -> s_load
    const float* __restrict__ gr = weight + o * LDW;

    // bias column (i=256, x_ext=1): every lane owns a full (b,o) sum -> init.
    float acc = gr[IN_DIM] * __builtin_amdgcn_sinf(wr[IN_DIM] * INV_2PI);

    // staging map: thread t -> row t>>2, float cols (t&3)*4..+3 and +16..+19
    // (lanes 0-3 cover a contiguous 64B row segment per load: coalesced)
    const int srow = t >> 2;
    const int scol = (t & 3) * 4;
    const float* xsrc = x + (b0 + srow) * IN_DIM + scol;

    // ---- prologue: stage chunk 0 into buffer 0 ----
    {
        const float4 a = *(const float4*)(xsrc + 0);
        const float4 b = *(const float4*)(xsrc + 16);
        float* d = &lx[0][srow * LXS + scol];
        *(float4*)(d +  0) = make_float4(a.x * INV_2PI, a.y * INV_2PI,
                                         a.z * INV_2PI, a.w * INV_2PI);
        *(float4*)(d + 16) = make_float4(b.x * INV_2PI, b.y * INV_2PI,
                                         b.z * INV_2PI, b.w * INV_2PI);
    }

#pragma unroll
    for (int c = 0; c < NCH; ++c) {
        // issue next chunk's global loads BEFORE the barrier: vmcnt latency
        // overlaps the barrier wait + this chunk's compute.
        float4 a, b;
        if (c + 1 < NCH) {
            a = *(const float4*)(xsrc + (c + 1) * CHUNK + 0);
            b = *(const float4*)(xsrc + (c + 1) * CHUNK + 16);
        }

        __syncthreads();   // stage(c) visible; all waves done reading buf c^1
        const int cur = c & 1;

        // write next chunk into the other buffer (its readers retired before
        // the barrier above; our compute below only touches lx[cur])
        if (c + 1 < NCH) {
            float* d = &lx[cur ^ 1][srow * LXS + scol];
            *(float4*)(d +  0) = make_float4(a.x * INV_2PI, a.y * INV_2PI,
                                             a.z * INV_2PI, a.w * INV_2PI);
            *(float4*)(d + 16) = make_float4(b.x * INV_2PI, b.y * INV_2PI,
                                             b.z * INV_2PI, b.w * INV_2PI);
        }

        // core: x straight from LDS (ds_read2_b32 pairs, 2-way alias free);
        // coefficients fold in via the scalar pipe (no coeff VALU instrs).
        const float* __restrict__ xr = &lx[cur][l * LXS];
        const int ib = c * CHUNK;
#pragma unroll
        for (int j = 0; j < CHUNK; ++j)
            acc = fmaf(gr[ib + j], __builtin_amdgcn_sinf(wr[ib + j] * xr[j]), acc);
    }

    // store: one coalesced-column store per wave (64 rows x 1 col)
    y[(b0 + l) * OUT_DIM + o] = acc;
}

extern "C" void kernel_launch(void* const* d_in, const int* in_sizes, int n_in,
                              void* d_out, int out_size, void* d_ws, size_t ws_size,
                              hipStream_t stream) {
    const float* x      = (const float*)d_in[0];
    const float* weight = (const float*)d_in[1];
    const float* wfreq  = (const float*)d_in[2];
    float* y            = (float*)d_out;

    const int B = in_sizes[0] / IN_DIM;                 // 2048
    const int grid = (B / 64) * (OUT_DIM / 4);          // 32 * 64 = 2048

    skan_kernel<<<grid, 256, 0, stream>>>(x, weight, wfreq, y);
}

// Round 7
// 86.362 us; speedup vs baseline: 4.8374x; 4.3563x over previous
//
#include <hip/hip_runtime.h>

// SKANLinear: y[b,o] = sum_{i=0}^{IN} weight[o,i] * sin(w[o,i] * x_ext[b,i])
// x_ext[b,IN] = 1.0. B=2048, IN=256, OUT=256. f32.
//
// R11: the 8-waves/SIMD experiment, attempt 3 — anti-spill via UNROLL 1.
// R9 spilled (xs[32] under 64-VGPR cap); R10 removed the array but STILL
// spilled ~1.3KB/thread: `#pragma unroll` flattened all 8 chunks, hoisting
// s_load batches + ds_reads into one live range that overran the cap.
// Common factor was {cap 64} x {full outer unroll}. Fix: `#pragma unroll 1`
// on the chunk loop — per-iteration live set ~40 VGPR (acc, 2 prefetch
// float4s, addresses, pipelined sin temps) < 64 cap. Inner 32-elem loop
// stays unrolled for ILP.
// Geometry (unchanged from R10): wave = 1 o x 64 b; coefficients via
// SMEM/SGPR folding; x pre-scaled by 1/2pi staged through LDS (stride-33,
// 2-way alias = free); double-buffered 32-i chunks, one barrier per chunk;
// global prefetch issued pre-barrier. LDS 16.9KB x 8 blocks = 135KB/CU;
// grid 2048 = exactly 8 blocks/CU = 8 waves/SIMD.
// Discriminator: occupancy covers stalls -> kernel 12-16us (dur ~62-68);
// neutral -> ~25us (dur ~76). Spill signature gone either way.

#define IN_DIM 256
#define OUT_DIM 256
#define LDW 257
#define CHUNK 32
#define NCH 8               // 256 / 32
#define LXS 33              // x-tile row stride (odd -> 2-way bank alias = free)
#define INV_2PI 0.15915494309189535f

__global__ __launch_bounds__(256, 8)
void skan_kernel(const float* __restrict__ x,      // [2048][256]
                 const float* __restrict__ weight, // [256][257]
                 const float* __restrict__ wfreq,  // [256][257]
                 float* __restrict__ y)            // [2048][256]
{
    __shared__ float lx[2][64 * LXS];   // 2 x 8448 B = 16.9 KB

    const int t  = threadIdx.x;
    const int l  = t & 63;                                   // lane = local b
    const int wv = __builtin_amdgcn_readfirstlane(t >> 6);   // wave id, uniform

    const int obase = (blockIdx.x & 63) * 4;    // 64 o-tiles of 4
    const int b0    = (blockIdx.x >> 6) * 64;   // 32 b-tiles of 64
    const int o     = obase + wv;               // ONE o per wave

    const float* __restrict__ wr = wfreq  + o * LDW;  // uniform -> s_load
    const float* __restrict__ gr = weight + o * LDW;

    // bias column (i=256, x_ext=1): every lane owns a full (b,o) sum -> init.
    float acc = gr[IN_DIM] * __builtin_amdgcn_sinf(wr[IN_DIM] * INV_2PI);

    // staging map: thread t -> row t>>2, float cols (t&3)*4..+3 and +16..+19
    // (lanes 0..3 cover a contiguous 64B row segment per load: coalesced)
    const int srow = t >> 2;
    const int scol = (t & 3) * 4;
    const float* xsrc = x + (b0 + srow) * IN_DIM + scol;

    // ---- prologue: stage chunk 0 into buffer 0 ----
    {
        const float4 a = *(const float4*)(xsrc + 0);
        const float4 b = *(const float4*)(xsrc + 16);
        float* d = &lx[0][srow * LXS + scol];
        *(float4*)(d +  0) = make_float4(a.x * INV_2PI, a.y * INV_2PI,
                                         a.z * INV_2PI, a.w * INV_2PI);
        *(float4*)(d + 16) = make_float4(b.x * INV_2PI, b.y * INV_2PI,
                                         b.z * INV_2PI, b.w * INV_2PI);
    }

#pragma unroll 1            // <- the anti-spill fix: keep live ranges local
    for (int c = 0; c < NCH; ++c) {
        // issue next chunk's global loads BEFORE the barrier: vmcnt latency
        // overlaps the barrier wait + this chunk's compute.
        float4 a, b;
        if (c + 1 < NCH) {
            a = *(const float4*)(xsrc + (c + 1) * CHUNK + 0);
            b = *(const float4*)(xsrc + (c + 1) * CHUNK + 16);
        }

        __syncthreads();   // stage(c) visible; all waves done reading buf c^1
        const int cur = c & 1;

        // write next chunk into the other buffer (its readers retired before
        // the barrier above; our compute below only touches lx[cur])
        if (c + 1 < NCH) {
            float* d = &lx[cur ^ 1][srow * LXS + scol];
            *(float4*)(d +  0) = make_float4(a.x * INV_2PI, a.y * INV_2PI,
                                             a.z * INV_2PI, a.w * INV_2PI);
            *(float4*)(d + 16) = make_float4(b.x * INV_2PI, b.y * INV_2PI,
                                             b.z * INV_2PI, b.w * INV_2PI);
        }

        // core: x straight from LDS (ds_read2_b32 pairs, 2-way alias free);
        // coefficients fold in via the scalar pipe (no coeff VALU instrs).
        const float* __restrict__ xr = &lx[cur][l * LXS];
        const int ib = c * CHUNK;
#pragma unroll
        for (int j = 0; j < CHUNK; ++j)
            acc = fmaf(gr[ib + j], __builtin_amdgcn_sinf(wr[ib + j] * xr[j]), acc);
    }

    // store: one coalesced-column store per wave (64 rows x 1 col)
    y[(b0 + l) * OUT_DIM + o] = acc;
}

extern "C" void kernel_launch(void* const* d_in, const int* in_sizes, int n_in,
                              void* d_out, int out_size, void* d_ws, size_t ws_size,
                              hipStream_t stream) {
    const float* x      = (const float*)d_in[0];
    const float* weight = (const float*)d_in[1];
    const float* wfreq  = (const float*)d_in[2];
    float* y            = (float*)d_out;

    const int B = in_sizes[0] / IN_DIM;                 // 2048
    const int grid = (B / 64) * (OUT_DIM / 4);          // 32 * 64 = 2048

    skan_kernel<<<grid, 256, 0, stream>>>(x, weight, wfreq, y);
}